// Round 7
// baseline (309.668 us; speedup 1.0000x reference)
//
#include <hip/hip_runtime.h>
#include <hip/hip_bf16.h>
#include <math.h>

// ---------------- ws layout (float offsets) ----------------
#define WQ0 0
#define BQ0 320
#define WQ1 384
#define BQ1 4480
#define WQ2 4544
#define BQ2 8640
#define WQ3 8704
#define BQ3 12800
#define WQ4 12864
#define BQ4 12928
#define GT0 12932
#define GT1 13444
#define GT2 15492
// Packed bf16 MFMA B-fragments (hi then lo): 24 frags x 64 lanes x 16B, x2.
#define FRAG_OFF 23684
#define NFRAG 24

typedef __bf16 bf16x8 __attribute__((ext_vector_type(8)));
typedef float floatx4 __attribute__((ext_vector_type(4)));
typedef float floatx2 __attribute__((ext_vector_type(2)));
typedef unsigned int uintx4 __attribute__((ext_vector_type(4)));

__device__ inline floatx4 mfma16(bf16x8 a, bf16x8 b, floatx4 c) {
    return __builtin_amdgcn_mfma_f32_16x16x32_bf16(a, b, c, 0, 0, 0);
}
__device__ inline floatx2 splat2(float c) { return (floatx2){c, c}; }
__device__ inline unsigned int fbits(float f) { return __builtin_bit_cast(unsigned int, f); }
__device__ inline float maskhi(float f) {
    return __builtin_bit_cast(float, fbits(f) & 0xffff0000u);
}
__device__ inline unsigned int pack_bf16(float a, float b) {
    unsigned short ua = __builtin_bit_cast(unsigned short, (__bf16)a);
    unsigned short ub = __builtin_bit_cast(unsigned short, (__bf16)b);
    return (unsigned int)ua | ((unsigned int)ub << 16);
}
// pack the top-16 (truncated bf16) of two floats: one v_perm_b32
__device__ inline unsigned int pack_hi2(float e0, float e1) {
    return __builtin_amdgcn_perm(fbits(e1), fbits(e0), 0x07060302u);
}

__device__ void block_minmax(float mn, float mx, float* omn, float* omx) {
    __shared__ float smn[4], smx[4];
    __syncthreads();
    #pragma unroll
    for (int off = 32; off > 0; off >>= 1) {
        mn = fminf(mn, __shfl_down(mn, off));
        mx = fmaxf(mx, __shfl_down(mx, off));
    }
    int wid = threadIdx.x >> 6, lane = threadIdx.x & 63;
    if (lane == 0) { smn[wid] = mn; smx[wid] = mx; }
    __syncthreads();
    if (threadIdx.x == 0) {
        float a = smn[0], b = smx[0];
        for (int i = 1; i < 4; ++i) { a = fminf(a, smn[i]); b = fmaxf(b, smx[i]); }
        smn[0] = a; smx[0] = b;
    }
    __syncthreads();
    *omn = smn[0]; *omx = smx[0];
}

// _qround forward: round((x-mn)/scale)*scale + mn, scale = max(mx-mn,1e-8)/63
__device__ void quantize_tensor(const float* __restrict__ src, int n, float* __restrict__ dst) {
    float mn = 3.4e38f, mx = -3.4e38f;
    for (int i = threadIdx.x; i < n; i += blockDim.x) {
        float v = src[i];
        mn = fminf(mn, v); mx = fmaxf(mx, v);
    }
    float gmn, gmx;
    block_minmax(mn, mx, &gmn, &gmx);
    float scale = fmaxf(gmx - gmn, 1e-8f) / 63.0f;
    for (int i = threadIdx.x; i < n; i += blockDim.x) {
        float v = src[i];
        dst[i] = rintf((v - gmn) / scale) * scale + gmn;
    }
}

// ONE prep launch:
//   blocks 0..9   : quantize the 10 weight/bias tensors into ws
//   blocks 10..20 : grid argmax tables (one thread per grid row)
//   blocks 21..44 : MFMA B-fragment pack for layers 1..3 (self-contained:
//                   each block redoes the wave-reduce min/max of its layer's
//                   4096 weights — min/max are order-independent, so the
//                   quantization is bit-identical to blocks 2/4/6's output).
__global__ void vinr_prep(
    const float* __restrict__ cb0, const float* __restrict__ ind0,
    const float* __restrict__ cb1, const float* __restrict__ ind1,
    const float* __restrict__ cb2, const float* __restrict__ ind2,
    const float* __restrict__ w0, const float* __restrict__ b0,
    const float* __restrict__ w1, const float* __restrict__ b1,
    const float* __restrict__ w2, const float* __restrict__ b2,
    const float* __restrict__ w3, const float* __restrict__ b3,
    const float* __restrict__ w4, const float* __restrict__ b4,
    float* __restrict__ ws)
{
    if (blockIdx.x < 10) {
        switch (blockIdx.x) {
            case 0: quantize_tensor(w0, 320, ws + WQ0); break;
            case 1: quantize_tensor(b0, 64, ws + BQ0); break;
            case 2: quantize_tensor(w1, 4096, ws + WQ1); break;
            case 3: quantize_tensor(b1, 64, ws + BQ1); break;
            case 4: quantize_tensor(w2, 4096, ws + WQ2); break;
            case 5: quantize_tensor(b2, 64, ws + BQ2); break;
            case 6: quantize_tensor(w3, 4096, ws + WQ3); break;
            case 7: quantize_tensor(b3, 64, ws + BQ3); break;
            case 8: quantize_tensor(w4, 64, ws + WQ4); break;
            case 9: quantize_tensor(b4, 1, ws + BQ4); break;
        }
    } else if (blockIdx.x < 21) {
        int r = (int)(blockIdx.x - 10) * (int)blockDim.x + (int)threadIdx.x;
        const float* ind; const float* cb; float* dst;
        if (r < 128)       { ind = ind0 + r * 64;          cb = cb0; dst = ws + GT0 + r * 4; }
        else if (r < 640)  { int rr = r - 128;  ind = ind1 + rr * 64; cb = cb1; dst = ws + GT1 + rr * 4; }
        else if (r < 2688) { int rr = r - 640;  ind = ind2 + rr * 64; cb = cb2; dst = ws + GT2 + rr * 4; }
        else return;
        float best = -3.4e38f; int bi = 0;
        for (int j = 0; j < 64; ++j) {
            float v = ind[j];
            if (v > best) { best = v; bi = j; }
        }
        #pragma unroll
        for (int d = 0; d < 4; ++d) dst[d] = cb[bi * 4 + d];
    } else {
        if (threadIdx.x >= 64) return;                 // one wave per frag
        int fi = (int)blockIdx.x - 21;                 // 0..23
        int lane = (int)threadIdx.x;
        int l = fi >> 3, s = (fi >> 2) & 1, nt = fi & 3;
        const float* w = (l == 0) ? w1 : (l == 1) ? w2 : w3;
        float mn = 3.4e38f, mx = -3.4e38f;
        for (int i = lane; i < 4096; i += 64) {
            float v = w[i];
            mn = fminf(mn, v); mx = fmaxf(mx, v);
        }
        #pragma unroll
        for (int off = 32; off > 0; off >>= 1) {
            mn = fminf(mn, __shfl_xor(mn, off));
            mx = fmaxf(mx, __shfl_xor(mx, off));
        }
        float scale = fmaxf(mx - mn, 1e-8f) / 63.0f;
        int q = lane >> 4, m15 = lane & 15;
        int n = nt * 16 + m15;
        bf16x8 hi, lo;
        #pragma unroll
        for (int j = 0; j < 8; ++j) {
            int k = s * 32 + q * 8 + j;
            float v = w[k * 64 + n];
            v = rintf((v - mn) / scale) * scale + mn;  // quantized weight
            __bf16 hb = (__bf16)v;
            hi[j] = hb;
            lo[j] = (__bf16)(v - (float)hb);
        }
        bf16x8* base = (bf16x8*)(ws + FRAG_OFF);
        base[fi * 64 + lane] = hi;
        base[NFRAG * 64 + fi * 64 + lane] = lo;
    }
}

// Packed-pair gelu: 0.5x + 0.5|x|*erf_mag(|x|/sqrt2), AS 7.1.26 erf (1.5e-7).
__device__ inline floatx2 gelu2(floatx2 x) {
    floatx2 ax = __builtin_elementwise_abs(x);
    floatx2 z  = ax * splat2(0.70710678118654752f);
    floatx2 den = __builtin_elementwise_fma(z, splat2(0.3275911f), splat2(1.0f));
    floatx2 t;
    t.x = __builtin_amdgcn_rcpf(den.x);
    t.y = __builtin_amdgcn_rcpf(den.y);
    floatx2 p = __builtin_elementwise_fma(t, splat2(1.061405429f), splat2(-1.453152027f));
    p = __builtin_elementwise_fma(t, p, splat2(1.421413741f));
    p = __builtin_elementwise_fma(t, p, splat2(-0.284496736f));
    p = __builtin_elementwise_fma(t, p, splat2(0.254829592f));
    p = p * t;
    floatx2 ea = (z * z) * splat2(-1.44269504088896f);
    floatx2 e;
    e.x = __builtin_amdgcn_exp2f(ea.x);
    e.y = __builtin_amdgcn_exp2f(ea.y);
    floatx2 er = __builtin_elementwise_fma(-p, e, splat2(1.0f));
    floatx2 hax = ax * splat2(0.5f);
    return __builtin_elementwise_fma(hax, er, x * splat2(0.5f));
}

__device__ inline float tanh_fast(float x) {
    float e = __builtin_amdgcn_exp2f(x * 2.88539008177793f);
    return fmaf(-2.0f, __builtin_amdgcn_rcpf(e + 1.0f), 1.0f);
}

// 16 points per wave; activations in wave-private LDS tile [16][68] f32
// (4352 B/wave, 17408 B/block -> 8 blocks/CU, 32 waves/CU).
// Layers 1-3: one 16x16 m-tile, 4 n-tiles, hi/lo bf16 split (3 MFMA each).
// Layers 0/4: each point's 64 features split across its quad's 4 lanes.
#define LSTR 68

__global__ __launch_bounds__(256, 8) void vinr_main(
    const float* __restrict__ x, const float* __restrict__ ws,
    float* __restrict__ out, int N)
{
    __shared__ __align__(16) float hlds[4 * 16 * LSTR];
    int wave = threadIdx.x >> 6, lane = threadIdx.x & 63;
    int q = lane >> 4, m15 = lane & 15;
    int j0 = q << 4;                       // feature quarter [j0, j0+16)
    float* slice = hlds + wave * (16 * LSTR);

    int idx = (int)blockIdx.x * 64 + wave * 16 + m15;
    int idxc = min(idx, N - 1);
    float2 xr = ((const float2*)x)[idxc];  // 4 lanes/point, L1-broadcast
    float feat  = xr.x;
    float coord = xr.y;

    float g0 = 0.f, g1 = 0.f, g2 = 0.f, g3 = 0.f;
    const int RES[3]  = {128, 512, 2048};
    const int GOFF[3] = {GT0, GT1, GT2};
    #pragma unroll
    for (int gi = 0; gi < 3; ++gi) {
        int res = RES[gi];
        float c = (coord + 1.0f) * 0.5f * (float)(res - 1);
        int left  = min((int)floorf(c), res - 2);
        int right = max((int)ceilf(c), 1);
        float w = c - (float)left;
        const float4* gt = (const float4*)(ws + GOFF[gi]);
        float4 gl = gt[left];
        float4 gr = gt[right];
        float wm = 1.0f - w;
        g0 += wm * gl.x + w * gr.x;
        g1 += wm * gl.y + w * gr.y;
        g2 += wm * gl.z + w * gr.z;
        g3 += wm * gl.w + w * gr.w;
    }

    // layer 0: 5 -> 64; this lane computes features [j0, j0+16) of point m15.
    {
        const floatx2* w0v = (const floatx2*)(ws + WQ0);  // row d pair-base d*32
        const floatx2* b0v = (const floatx2*)(ws + BQ0);
        float* row = slice + m15 * LSTR + j0;
        int jh = j0 >> 1;
        #pragma unroll
        for (int jj = 0; jj < 8; ++jj) {
            floatx2 a = b0v[jh + jj];
            a = __builtin_elementwise_fma(splat2(g0),   w0v[jh + jj],        a);
            a = __builtin_elementwise_fma(splat2(g1),   w0v[32 + jh + jj],   a);
            a = __builtin_elementwise_fma(splat2(g2),   w0v[64 + jh + jj],   a);
            a = __builtin_elementwise_fma(splat2(g3),   w0v[96 + jh + jj],   a);
            a = __builtin_elementwise_fma(splat2(feat), w0v[128 + jh + jj],  a);
            *(floatx2*)(row + 2 * jj) = gelu2(a);
        }
    }

    const bf16x8* fh = (const bf16x8*)(ws + FRAG_OFF);
    const bf16x8* fl = fh + NFRAG * 64;
    const int BQL[3] = {BQ1, BQ2, BQ3};

    #pragma unroll 1
    for (int l = 0; l < 3; ++l) {
        floatx4 acc[4];
        #pragma unroll
        for (int nt = 0; nt < 4; ++nt) acc[nt] = (floatx4){0.f, 0.f, 0.f, 0.f};

        #pragma unroll
        for (int s = 0; s < 2; ++s) {
            // A-fragment: lane holds A[m=m15][k=s*32+q*8+j]
            const float* ap = slice + m15 * LSTR + s * 32 + q * 8;
            float4 xa = *(const float4*)ap;
            float4 xb = *(const float4*)(ap + 4);
            unsigned int h01 = pack_hi2(xa.x, xa.y);
            unsigned int h23 = pack_hi2(xa.z, xa.w);
            unsigned int h45 = pack_hi2(xb.x, xb.y);
            unsigned int h67 = pack_hi2(xb.z, xb.w);
            unsigned int l01 = pack_bf16(xa.x - maskhi(xa.x), xa.y - maskhi(xa.y));
            unsigned int l23 = pack_bf16(xa.z - maskhi(xa.z), xa.w - maskhi(xa.w));
            unsigned int l45 = pack_bf16(xb.x - maskhi(xb.x), xb.y - maskhi(xb.y));
            unsigned int l67 = pack_bf16(xb.z - maskhi(xb.z), xb.w - maskhi(xb.w));
            bf16x8 Ah = __builtin_bit_cast(bf16x8, (uintx4){h01, h23, h45, h67});
            bf16x8 Al = __builtin_bit_cast(bf16x8, (uintx4){l01, l23, l45, l67});
            #pragma unroll
            for (int nt = 0; nt < 4; ++nt) {
                int fi = (l * 2 + s) * 4 + nt;
                bf16x8 Bh = fh[fi * 64 + lane];
                bf16x8 Bl = fl[fi * 64 + lane];
                acc[nt] = mfma16(Ah, Bh, acc[nt]);
                acc[nt] = mfma16(Ah, Bl, acc[nt]);
                acc[nt] = mfma16(Al, Bh, acc[nt]);
            }
        }
        // epilogue: +bias, gelu (packed pairs), store back.
        // C layout: row = q*4+r (point), col = m15 (feature within n-tile).
        const float* bq = ws + BQL[l];
        #pragma unroll
        for (int nt = 0; nt < 4; ++nt) {
            float bias = bq[nt * 16 + m15];
            floatx4 av = acc[nt];
            floatx2 v01 = gelu2((floatx2){av[0] + bias, av[1] + bias});
            floatx2 v23 = gelu2((floatx2){av[2] + bias, av[3] + bias});
            float* wbase = slice + (q * 4) * LSTR + nt * 16 + m15;
            wbase[0]        = v01.x;
            wbase[LSTR]     = v01.y;
            wbase[2 * LSTR] = v23.x;
            wbase[3 * LSTR] = v23.y;
        }
    }

    // layer 4: quarter-dot over features [j0, j0+16) of point m15, then
    // combine the 4 quads via shfl and tanh on quad 0.
    {
        const floatx2* w4v = (const floatx2*)(ws + WQ4);
        float acc4 = (q == 0) ? ws[BQ4] : 0.0f;
        const float* row = slice + m15 * LSTR + j0;
        int jh = j0 >> 1;
        floatx2 a2 = splat2(0.0f);
        #pragma unroll
        for (int c = 0; c < 4; ++c) {
            float4 v = *(const float4*)(row + 4 * c);
            a2 = __builtin_elementwise_fma((floatx2){v.x, v.y}, w4v[jh + 2 * c],     a2);
            a2 = __builtin_elementwise_fma((floatx2){v.z, v.w}, w4v[jh + 2 * c + 1], a2);
        }
        acc4 += a2.x + a2.y;
        acc4 += __shfl_xor(acc4, 16);
        acc4 += __shfl_xor(acc4, 32);
        if (q == 0 && idx < N) out[idx] = tanh_fast(acc4);
    }
}

extern "C" void kernel_launch(void* const* d_in, const int* in_sizes, int n_in,
                              void* d_out, int out_size, void* d_ws, size_t ws_size,
                              hipStream_t stream) {
    const float* x    = (const float*)d_in[0];
    const float* cb0  = (const float*)d_in[1];
    const float* ind0 = (const float*)d_in[2];
    const float* cb1  = (const float*)d_in[3];
    const float* ind1 = (const float*)d_in[4];
    const float* cb2  = (const float*)d_in[5];
    const float* ind2 = (const float*)d_in[6];
    const float* w0 = (const float*)d_in[7],  * b0 = (const float*)d_in[8];
    const float* w1 = (const float*)d_in[9],  * b1 = (const float*)d_in[10];
    const float* w2 = (const float*)d_in[11], * b2 = (const float*)d_in[12];
    const float* w3 = (const float*)d_in[13], * b3 = (const float*)d_in[14];
    const float* w4 = (const float*)d_in[15], * b4 = (const float*)d_in[16];
    float* ws  = (float*)d_ws;
    float* out = (float*)d_out;

    int N = in_sizes[0] / 2;  // 1<<20

    vinr_prep<<<45, 256, 0, stream>>>(cb0, ind0, cb1, ind1, cb2, ind2,
                                      w0, b0, w1, b1, w2, b2, w3, b3, w4, b4, ws);
    int blocks = (N + 63) / 64;
    vinr_main<<<blocks, 256, 0, stream>>>(x, ws, out, N);
}